// Round 15
// baseline (46.025 us; speedup 1.0000x reference)
//
#include <hip/hip_runtime.h>

// (min,+) DP, wave-specialized. 2 images/block, 8 waves, grid=256 (1/CU):
//   wave 0: chain image A    wave 1: chain image B
//   waves 2-7: prep, 3 per image (rows 0-10 / 11-21 / 22-31 of each chunk)
// CH=32, NCH=8: only 8 barriers/image (barrier+ds-ramp cost was ~25% at
// CH=8). Chain reads chunks in 4x8-row groups with next group's ds_reads
// issued before stepping current (LDS latency hidden). LDS 128KB, 1 blk/CU
// is grid-enforced (256 blocks = 256 CUs) so big LDS costs nothing.

#define HH 256
#define WW 256
#define CH 32          // rows per chunk
#define NCH 8          // chunks per image
#define NULLV 1e30f

#define SBAR() __builtin_amdgcn_sched_barrier(0)

template<int CTRL, int ROWM>
__device__ __forceinline__ float dpp_mov(float x, float oldv) {
    return __builtin_bit_cast(float, __builtin_amdgcn_update_dpp(
        __builtin_bit_cast(int, oldv), __builtin_bit_cast(int, x),
        CTRL, ROWM, 0xF, false));
}

__device__ __forceinline__ float wave_iscan_add(float x) {
    x += dpp_mov<0x111, 0xF>(x, 0.0f);  // row_shr:1
    x += dpp_mov<0x112, 0xF>(x, 0.0f);  // row_shr:2
    x += dpp_mov<0x114, 0xF>(x, 0.0f);  // row_shr:4
    x += dpp_mov<0x118, 0xF>(x, 0.0f);  // row_shr:8
    x += dpp_mov<0x142, 0xA>(x, 0.0f);  // row_bcast:15 -> rows 1,3
    x += dpp_mov<0x143, 0xC>(x, 0.0f);  // row_bcast:31 -> rows 2,3
    return x;
}

__device__ __forceinline__ float wave_iscan_min(float x) {
    x = fminf(x, dpp_mov<0x111, 0xF>(x, NULLV));
    x = fminf(x, dpp_mov<0x112, 0xF>(x, NULLV));
    x = fminf(x, dpp_mov<0x114, 0xF>(x, NULLV));
    x = fminf(x, dpp_mov<0x118, 0xF>(x, NULLV));
    x = fminf(x, dpp_mov<0x142, 0xA>(x, NULLV));
    x = fminf(x, dpp_mov<0x143, 0xC>(x, NULLV));
    return x;
}

__device__ __forceinline__ float softplus_f(float x) {
    float ax = fabsf(x);
    float t  = __expf(-ax);
    return fmaxf(x, 0.0f) + __logf(1.0f + t);
}

// full-row cumsum of softplus for one row; returns S at cols 4l..4l+3
__device__ __forceinline__ float4 prep_row(float4 c) {
    float t0 = softplus_f(c.x);
    float t1 = t0 + softplus_f(c.y);
    float t2 = t1 + softplus_f(c.z);
    float t3 = t2 + softplus_f(c.w);
    float s    = wave_iscan_add(t3);
    float soff = dpp_mov<0x138, 0xF>(s, 0.0f);  // wave_shr:1, lane0 -> 0
    return make_float4(soff + t0, soff + t1, soff + t2, soff + t3);
}

// prep worker: NR consecutive rows (chunk-offset row0) of every chunk.
// Next chunk's loads issued before current chunk's compute (loop-carried).
template<int NR>
__device__ __forceinline__ void prep_run(const float4* gp, int row0,
                                         float* b0, float* b1, int lane) {
    float4 L[NR];
#pragma unroll
    for (int i = 0; i < NR; ++i) L[i] = gp[(size_t)(row0 + i) * 64];
    SBAR();
    for (int k = 0; k < NCH; ++k) {
        float4 N[NR];
#pragma unroll
        for (int i = 0; i < NR; ++i) N[i] = L[i];
        if (k + 1 < NCH) {
            const size_t rn = (size_t)(k + 1) * CH + row0;
#pragma unroll
            for (int i = 0; i < NR; ++i) N[i] = gp[(rn + i) * 64];
        }
        SBAR();
        float* buf = (k & 1) ? b1 : b0;
#pragma unroll
        for (int i = 0; i < NR; ++i)
            *reinterpret_cast<float4*>(&buf[i * WW + lane * 4]) = prep_row(L[i]);
        __syncthreads();                       // publish chunk k
#pragma unroll
        for (int i = 0; i < NR; ++i) L[i] = N[i];
    }
}

__global__ __launch_bounds__(512, 1) void dp_kernel(const float* __restrict__ img,
                                                    float* __restrict__ out) {
    const int tid = threadIdx.x;
    const int wid = tid >> 6;
    const int lane = tid & 63;

    // [image][buffer][row][col] -> 128 KB
    __shared__ __align__(16) float sbuf[2][2][CH][WW];

    if (wid < 2) {
        // ---------------- chain waves (one per image) ----------------
        const int imgi = wid;
        __builtin_amdgcn_s_setprio(1);
        float v0, v1, v2, v3;

        auto row_step = [&](const float4& S) {
            float soff = dpp_mov<0x138, 0xF>(S.w, 0.0f);  // S[4l-1]
            float vm1  = dpp_mov<0x138, 0xF>(v3, NULLV);  // v[4l-1]
            float B0 = fminf(v0, vm1) - soff;
            float B1 = fminf(v1, v0) - S.x;
            float B2 = fminf(v2, v1) - S.y;
            float B3 = fminf(v3, v2) - S.z;
            float m1 = fminf(B0, B1);
            float m2 = fminf(m1, B2);
            float m3 = fminf(m2, B3);
            float mm   = wave_iscan_min(m3);
            float moff = dpp_mov<0x138, 0xF>(mm, NULLV);
            v0 = S.x + fminf(moff, B0);
            v1 = S.y + fminf(moff, m1);
            v2 = S.z + fminf(moff, m2);
            v3 = S.w + fminf(moff, m3);
        };

#define RD8(P, buf, r0)                                                  \
    P##0 = *reinterpret_cast<const float4*>(&(buf)[(r0) + 0][lane * 4]); \
    P##1 = *reinterpret_cast<const float4*>(&(buf)[(r0) + 1][lane * 4]); \
    P##2 = *reinterpret_cast<const float4*>(&(buf)[(r0) + 2][lane * 4]); \
    P##3 = *reinterpret_cast<const float4*>(&(buf)[(r0) + 3][lane * 4]); \
    P##4 = *reinterpret_cast<const float4*>(&(buf)[(r0) + 4][lane * 4]); \
    P##5 = *reinterpret_cast<const float4*>(&(buf)[(r0) + 5][lane * 4]); \
    P##6 = *reinterpret_cast<const float4*>(&(buf)[(r0) + 6][lane * 4]); \
    P##7 = *reinterpret_cast<const float4*>(&(buf)[(r0) + 7][lane * 4]);
#define ST8(P)                                                           \
    row_step(P##0); row_step(P##1); row_step(P##2); row_step(P##3);      \
    row_step(P##4); row_step(P##5); row_step(P##6); row_step(P##7);

        float4 A0, A1, A2, A3, A4, A5, A6, A7;
        float4 B0, B1, B2, B3, B4, B5, B6, B7;

        // chunk 0 (peel row-0 init)
        __syncthreads();
        {
            const float(*buf)[WW] = sbuf[imgi][0];
            RD8(A, buf, 0); RD8(B, buf, 8);
            v0 = A0.x; v1 = A0.y; v2 = A0.z; v3 = A0.w;
            row_step(A1); row_step(A2); row_step(A3);
            row_step(A4); row_step(A5); row_step(A6); row_step(A7);
            RD8(A, buf, 16);
            ST8(B);
            RD8(B, buf, 24);
            ST8(A);
            ST8(B);
        }
        // chunks 1..7
        for (int k = 1; k < NCH; ++k) {
            __syncthreads();
            const float(*buf)[WW] = sbuf[imgi][k & 1];
            RD8(A, buf, 0); RD8(B, buf, 8);
            ST8(A);
            RD8(A, buf, 16);
            ST8(B);
            RD8(B, buf, 24);
            ST8(A);
            ST8(B);
        }
#undef RD8
#undef ST8
        if (lane == 63) out[2 * blockIdx.x + imgi] = v3;
    } else {
        // ---------------- prep waves: 3 per image (11/11/10 rows) ----------------
        const int imgi = (wid - 2) & 1;        // waves 2,4,6 -> A; 3,5,7 -> B
        const int pw   = (wid - 2) >> 1;       // 0,1,2
        const float* gbase = img + (size_t)(2 * blockIdx.x + imgi) * HH * WW;
        const float4* gp = reinterpret_cast<const float4*>(gbase) + lane;
        const int row0 = pw * 11;              // 0, 11, 22
        float* b0 = &sbuf[imgi][0][row0][0];
        float* b1 = &sbuf[imgi][1][row0][0];
        if (pw < 2) prep_run<11>(gp, row0, b0, b1, lane);
        else        prep_run<10>(gp, row0, b0, b1, lane);
    }
}

extern "C" void kernel_launch(void* const* d_in, const int* in_sizes, int n_in,
                              void* d_out, int out_size, void* d_ws, size_t ws_size,
                              hipStream_t stream) {
    const float* img = (const float*)d_in[0];
    float* out = (float*)d_out;
    dp_kernel<<<out_size / 2, 512, 0, stream>>>(img, out);
}